// Round 1
// baseline (218.774 us; speedup 1.0000x reference)
//
#include <hip/hip_runtime.h>
#include <stdint.h>

typedef __bf16 bf16x8 __attribute__((ext_vector_type(8)));
typedef float f32x4 __attribute__((ext_vector_type(4)));

static constexpr int B_ = 2, S_ = 2048, D_ = 1024, H_ = 16, HD_ = 64;
static constexpr int M_ = B_ * S_;                         // 4096
static constexpr size_t HSZ = (size_t)B_ * H_ * S_ * HD_;  // 4,194,304 elems per Q/K/V

#define DEV_INLINE __device__ __forceinline__

DEV_INLINE uint16_t f2bf(float f) {
  uint32_t u = __builtin_bit_cast(uint32_t, f);
  u += 0x7fff + ((u >> 16) & 1);   // RNE; inputs are finite
  return (uint16_t)(u >> 16);
}

#define GLD16(gptr, lptr)                                                        \
  __builtin_amdgcn_global_load_lds(                                              \
      (const __attribute__((address_space(1))) void*)(gptr),                     \
      (__attribute__((address_space(3))) void*)(lptr), 16, 0, 0)

// ---------------- x -> bf16 ----------------
__global__ void cvt_x_kernel(const float* __restrict__ x, uint16_t* __restrict__ xb) {
  int i = blockIdx.x * 256 + threadIdx.x;
  float4 v = reinterpret_cast<const float4*>(x)[i];
  ushort4 o;
  o.x = f2bf(v.x); o.y = f2bf(v.y); o.z = f2bf(v.z); o.w = f2bf(v.w);
  reinterpret_cast<ushort4*>(xb)[i] = o;
}

// ---------------- W (4x) -> W^T bf16, concatenated [4*1024][1024] ----------------
__global__ void tr_w_kernel(const float* __restrict__ W0, const float* __restrict__ W1,
                            const float* __restrict__ W2, const float* __restrict__ W3,
                            uint16_t* __restrict__ Wt) {
  __shared__ float tile[32][33];
  const float* W = (blockIdx.z == 0) ? W0 : (blockIdx.z == 1) ? W1
                   : (blockIdx.z == 2) ? W2 : W3;
  uint16_t* dst = Wt + (size_t)blockIdx.z * D_ * D_;
  int c = blockIdx.x * 32 + threadIdx.x;   // source col n
  int r0 = blockIdx.y * 32;                // source row k
#pragma unroll
  for (int j = threadIdx.y; j < 32; j += 8)
    tile[j][threadIdx.x] = W[(size_t)(r0 + j) * D_ + c];
  __syncthreads();
  int oc = blockIdx.y * 32 + threadIdx.x;  // dest col  = k
  int or0 = blockIdx.x * 32;               // dest row  = n
#pragma unroll
  for (int j = threadIdx.y; j < 32; j += 8)
    dst[(size_t)(or0 + j) * D_ + oc] = f2bf(tile[threadIdx.x][j]);
}

// ---------------- GEMM: C[M][N] = A[M][K] * Bt[N][K]^T ----------------
// EPI=0: scatter to QKV [3][B,H,S,HD] bf16.  EPI=1: f32 out + bias.
template <int EPI>
__global__ __launch_bounds__(256, 2)
void gemm_bt_kernel(const uint16_t* __restrict__ A, const uint16_t* __restrict__ Bt,
                    uint16_t* __restrict__ Cb, float* __restrict__ Cf,
                    const float* __restrict__ bias, int K) {
  __shared__ uint16_t lds[2][2][128 * 32];   // [buf][A/B][row][k] linear
  const int tid = threadIdx.x;
  const int lane = tid & 63;
  const int wid = tid >> 6;
  const int lo = lane & 15, hi = lane >> 4;
  const int row0 = blockIdx.y * 128, col0 = blockIdx.x * 128;
  const int wr = (wid >> 1) * 64, wc = (wid & 1) * 64;

  const uint16_t* gA = A + (size_t)(row0 + (tid >> 2)) * K + (tid & 3) * 8;
  const uint16_t* gB = Bt + (size_t)(col0 + (tid >> 2)) * K + (tid & 3) * 8;

  f32x4 acc[4][4] = {};

  auto stage = [&](int kt, int buf) {
    const uint16_t* a = gA + kt * 32;
    const uint16_t* b = gB + kt * 32;
    char* la = (char*)&lds[buf][0][0] + tid * 16;
    char* lb = (char*)&lds[buf][1][0] + tid * 16;
    GLD16(a, la);
    GLD16(a + (size_t)64 * K, la + 4096);
    GLD16(b, lb);
    GLD16(b + (size_t)64 * K, lb + 4096);
  };

  const int nk = K >> 5;
  stage(0, 0);
  __syncthreads();
  for (int kt = 0; kt < nk; ++kt) {
    const int cur = kt & 1;
    if (kt + 1 < nk) stage(kt + 1, cur ^ 1);
    const uint16_t* lA = &lds[cur][0][0];
    const uint16_t* lB = &lds[cur][1][0];
    bf16x8 af[4], bfr[4];
#pragma unroll
    for (int m = 0; m < 4; ++m)
      af[m] = *(const bf16x8*)(lA + (wr + m * 16 + lo) * 32 + hi * 8);
#pragma unroll
    for (int n = 0; n < 4; ++n)
      bfr[n] = *(const bf16x8*)(lB + (wc + n * 16 + lo) * 32 + hi * 8);
#pragma unroll
    for (int m = 0; m < 4; ++m)
#pragma unroll
      for (int n = 0; n < 4; ++n)
        acc[m][n] = __builtin_amdgcn_mfma_f32_16x16x32_bf16(af[m], bfr[n], acc[m][n], 0, 0, 0);
    __syncthreads();
  }

#pragma unroll
  for (int m = 0; m < 4; ++m)
#pragma unroll
    for (int n = 0; n < 4; ++n)
#pragma unroll
      for (int j = 0; j < 4; ++j) {
        int gr = row0 + wr + m * 16 + hi * 4 + j;
        int gc = col0 + wc + n * 16 + lo;
        float v = acc[m][n][j];
        if (EPI == 0) {
          int which = gc >> 10, c = gc & 1023;
          int hh = c >> 6, d = c & 63;
          int b = gr >> 11, s = gr & 2047;
          Cb[(size_t)which * HSZ + (((size_t)(b * H_ + hh) * S_ + s) * HD_ + d)] = f2bf(v);
        } else {
          Cf[(size_t)gr * D_ + gc] = v + bias[gc];
        }
      }
}

// ---------------- causal flash attention ----------------
// grid (S/128, H, B), 256 threads (4 waves), wave w owns q rows [bq*128+w*32, +32)
__global__ __launch_bounds__(256, 2)
void attn_kernel(const uint16_t* __restrict__ QKV, uint16_t* __restrict__ ctx) {
  __shared__ uint16_t ldsK[2 * 64 * 32];  // [s=d/32][kv][d%32]
  __shared__ uint16_t ldsV[2 * 64 * 32];  // [s=kv/32][d][kv%32]  (V^T)
  __shared__ uint16_t ldsP[128 * 72];     // [q][kv] padded 64->72

  const int tid = threadIdx.x;
  const int lane = tid & 63;
  const int w = tid >> 6;
  const int lo = lane & 15, hi = lane >> 4;

  const int bq = blockIdx.x, h = blockIdx.y, b = blockIdx.z;
  const size_t bh = ((size_t)(b * H_ + h)) * S_ * HD_;
  const uint16_t* Q  = QKV + bh;
  const uint16_t* Kp = QKV + HSZ + bh;
  const uint16_t* Vp = QKV + 2 * HSZ + bh;

  const int q0 = bq * 128 + w * 32;

  bf16x8 aq[2][2];
#pragma unroll
  for (int m = 0; m < 2; ++m)
#pragma unroll
    for (int ks = 0; ks < 2; ++ks)
      aq[m][ks] = *(const bf16x8*)(Q + (size_t)(q0 + m * 16 + lo) * HD_ + ks * 32 + hi * 8);

  float mstate[2][4], lstate[2][4];
  f32x4 acco[2][4] = {};
#pragma unroll
  for (int m = 0; m < 2; ++m)
#pragma unroll
    for (int j = 0; j < 4; ++j) { mstate[m][j] = -1e30f; lstate[m][j] = 0.f; }

  const float SC2 = 0.125f * 1.4426950408889634f;  // 1/sqrt(64) * log2(e)
  const int nkv = (bq + 1) * 2;

  for (int kt = 0; kt < nkv; ++kt) {
    const int kv0 = kt * 64;
    if (kt) __syncthreads();
    // stage K as two [64][32] sub-tiles (rows 64B -> 2-way conflicts only)
    {
      const uint16_t* gk = Kp + (size_t)(kv0 + (tid >> 2)) * HD_ + (tid & 3) * 8;
      char* lk = (char*)ldsK + tid * 16;
      GLD16(gk, lk);            // d 0..31
      GLD16(gk + 32, lk + 4096);// d 32..63
    }
    // stage V^T (manual transpose)
#pragma unroll
    for (int r = 0; r < 2; ++r) {
      int kvv = tid >> 3;            // 0..31
      int d0 = (tid & 7) * 8;
      int4 tmp = *(const int4*)(Vp + (size_t)(kv0 + r * 32 + kvv) * HD_ + d0);
      const uint16_t* v8 = (const uint16_t*)&tmp;
#pragma unroll
      for (int i2 = 0; i2 < 8; ++i2)
        ldsV[r * 2048 + (d0 + i2) * 32 + kvv] = v8[i2];
    }
    __syncthreads();

    // S = Q K^T
    bf16x8 bk[4][2];
#pragma unroll
    for (int n = 0; n < 4; ++n)
#pragma unroll
      for (int ks = 0; ks < 2; ++ks)
        bk[n][ks] = *(const bf16x8*)(ldsK + ks * 2048 + (n * 16 + lo) * 32 + hi * 8);

    f32x4 s4[2][4];
#pragma unroll
    for (int m = 0; m < 2; ++m)
#pragma unroll
      for (int n = 0; n < 4; ++n) {
        f32x4 z = {};
        z = __builtin_amdgcn_mfma_f32_16x16x32_bf16(aq[m][0], bk[n][0], z, 0, 0, 0);
        s4[m][n] = __builtin_amdgcn_mfma_f32_16x16x32_bf16(aq[m][1], bk[n][1], z, 0, 0, 0);
      }

    // scale (base-2) + causal mask
#pragma unroll
    for (int m = 0; m < 2; ++m)
#pragma unroll
      for (int n = 0; n < 4; ++n)
#pragma unroll
        for (int j = 0; j < 4; ++j) {
          int qg = q0 + m * 16 + hi * 4 + j;
          int kg = kv0 + n * 16 + lo;
          float v = s4[m][n][j] * SC2;
          s4[m][n][j] = (kg > qg) ? -1e30f : v;
        }

    // online softmax (row = over n in-reg + low-4 lane bits)
    float scj[2][4];
#pragma unroll
    for (int m = 0; m < 2; ++m)
#pragma unroll
      for (int j = 0; j < 4; ++j) {
        float vmax = fmaxf(fmaxf(s4[m][0][j], s4[m][1][j]), fmaxf(s4[m][2][j], s4[m][3][j]));
        vmax = fmaxf(vmax, __shfl_xor(vmax, 1));
        vmax = fmaxf(vmax, __shfl_xor(vmax, 2));
        vmax = fmaxf(vmax, __shfl_xor(vmax, 4));
        vmax = fmaxf(vmax, __shfl_xor(vmax, 8));
        float mnew = fmaxf(mstate[m][j], vmax);
        float sc = exp2f(mstate[m][j] - mnew);
        mstate[m][j] = mnew;
        float rsum = 0.f;
#pragma unroll
        for (int n = 0; n < 4; ++n) {
          float pv = exp2f(s4[m][n][j] - mnew);
          s4[m][n][j] = pv;
          rsum += pv;
        }
        rsum += __shfl_xor(rsum, 1);
        rsum += __shfl_xor(rsum, 2);
        rsum += __shfl_xor(rsum, 4);
        rsum += __shfl_xor(rsum, 8);
        lstate[m][j] = lstate[m][j] * sc + rsum;
        scj[m][j] = sc;
      }

    // rescale O, write P (wave-local rows -> no barrier needed)
#pragma unroll
    for (int m = 0; m < 2; ++m)
#pragma unroll
      for (int n = 0; n < 4; ++n)
#pragma unroll
        for (int j = 0; j < 4; ++j) {
          acco[m][n][j] *= scj[m][j];
          int ql = w * 32 + m * 16 + hi * 4 + j;
          ldsP[ql * 72 + n * 16 + lo] = f2bf(s4[m][n][j]);
        }

    // O += P V
    bf16x8 ap[2][2], bv[4][2];
#pragma unroll
    for (int m = 0; m < 2; ++m)
#pragma unroll
      for (int ks = 0; ks < 2; ++ks)
        ap[m][ks] = *(const bf16x8*)(ldsP + (w * 32 + m * 16 + lo) * 72 + ks * 32 + hi * 8);
#pragma unroll
    for (int n = 0; n < 4; ++n)
#pragma unroll
      for (int ks = 0; ks < 2; ++ks)
        bv[n][ks] = *(const bf16x8*)(ldsV + ks * 2048 + (n * 16 + lo) * 32 + hi * 8);
#pragma unroll
    for (int m = 0; m < 2; ++m)
#pragma unroll
      for (int n = 0; n < 4; ++n) {
        acco[m][n] = __builtin_amdgcn_mfma_f32_16x16x32_bf16(ap[m][0], bv[n][0], acco[m][n], 0, 0, 0);
        acco[m][n] = __builtin_amdgcn_mfma_f32_16x16x32_bf16(ap[m][1], bv[n][1], acco[m][n], 0, 0, 0);
      }
  }

  // normalize + write ctx [b*S+q][h*64+d] bf16
#pragma unroll
  for (int m = 0; m < 2; ++m)
#pragma unroll
    for (int j = 0; j < 4; ++j) {
      float inv = 1.f / lstate[m][j];
      int qg = q0 + m * 16 + hi * 4 + j;
      size_t row = (size_t)b * S_ + qg;
#pragma unroll
      for (int n = 0; n < 4; ++n)
        ctx[row * D_ + h * HD_ + n * 16 + lo] = f2bf(acco[m][n][j] * inv);
    }
}

extern "C" void kernel_launch(void* const* d_in, const int* in_sizes, int n_in,
                              void* d_out, int out_size, void* d_ws, size_t ws_size,
                              hipStream_t stream) {
  (void)in_sizes; (void)n_in; (void)out_size; (void)ws_size;
  const float* x  = (const float*)d_in[0];
  const float* Wq = (const float*)d_in[1];
  const float* Wk = (const float*)d_in[2];
  const float* Wv = (const float*)d_in[3];
  const float* Wo = (const float*)d_in[4];
  const float* bo = (const float*)d_in[5];
  float* out = (float*)d_out;

  uint16_t* ws  = (uint16_t*)d_ws;
  uint16_t* xb  = ws;                         // 4096*1024
  uint16_t* Wt  = xb + (size_t)M_ * D_;       // 4*1024*1024
  uint16_t* QKV = Wt + (size_t)4 * D_ * D_;   // 3*HSZ
  uint16_t* ctx = QKV + 3 * HSZ;              // 4096*1024   (~50 MB total)

  cvt_x_kernel<<<(M_ * D_) / 1024, 256, 0, stream>>>(x, xb);
  tr_w_kernel<<<dim3(32, 32, 4), dim3(32, 8), 0, stream>>>(Wq, Wk, Wv, Wo, Wt);
  gemm_bt_kernel<0><<<dim3(3072 / 128, M_ / 128), 256, 0, stream>>>(xb, Wt, QKV, nullptr, nullptr, D_);
  attn_kernel<<<dim3(S_ / 128, H_, B_), 256, 0, stream>>>(QKV, ctx);
  gemm_bt_kernel<1><<<dim3(D_ / 128, M_ / 128), 256, 0, stream>>>(ctx, Wt + (size_t)3 * D_ * D_, nullptr, out, bo, D_);
}

// Round 2
// 138.461 us; speedup vs baseline: 1.5800x; 1.5800x over previous
//
#include <hip/hip_runtime.h>
#include <stdint.h>

typedef __bf16 bf16x8 __attribute__((ext_vector_type(8)));
typedef float f32x4 __attribute__((ext_vector_type(4)));

static constexpr int B_ = 2, S_ = 2048, D_ = 1024, H_ = 16, HD_ = 64;
static constexpr int M_ = B_ * S_;                         // 4096
static constexpr size_t HSZ = (size_t)B_ * H_ * S_ * HD_;  // 4,194,304 elems per Q/K/V

#define DEV_INLINE __device__ __forceinline__

// 1/sqrt(HD) * log2(e) -- folded into Q at projection time (softmax runs base-2)
#define SC2F (0.125f * 1.4426950408889634f)

DEV_INLINE uint16_t f2bf(float f) {
  uint32_t u = __builtin_bit_cast(uint32_t, f);
  u += 0x7fff + ((u >> 16) & 1);   // RNE; inputs are finite
  return (uint16_t)(u >> 16);
}

#define GLD16(gptr, lptr)                                                        \
  __builtin_amdgcn_global_load_lds(                                              \
      (const __attribute__((address_space(1))) void*)(gptr),                     \
      (__attribute__((address_space(3))) void*)(lptr), 16, 0, 0)

// ---------------- x -> bf16 ----------------
__global__ void cvt_x_kernel(const float* __restrict__ x, uint16_t* __restrict__ xb) {
  int i = blockIdx.x * 256 + threadIdx.x;
  float4 v = reinterpret_cast<const float4*>(x)[i];
  ushort4 o;
  o.x = f2bf(v.x); o.y = f2bf(v.y); o.z = f2bf(v.z); o.w = f2bf(v.w);
  reinterpret_cast<ushort4*>(xb)[i] = o;
}

// ---------------- W (4x) -> W^T bf16, concatenated [4*1024][1024] ----------------
__global__ void tr_w_kernel(const float* __restrict__ W0, const float* __restrict__ W1,
                            const float* __restrict__ W2, const float* __restrict__ W3,
                            uint16_t* __restrict__ Wt) {
  __shared__ float tile[32][33];
  const float* W = (blockIdx.z == 0) ? W0 : (blockIdx.z == 1) ? W1
                   : (blockIdx.z == 2) ? W2 : W3;
  uint16_t* dst = Wt + (size_t)blockIdx.z * D_ * D_;
  int c = blockIdx.x * 32 + threadIdx.x;   // source col n
  int r0 = blockIdx.y * 32;                // source row k
#pragma unroll
  for (int j = threadIdx.y; j < 32; j += 8)
    tile[j][threadIdx.x] = W[(size_t)(r0 + j) * D_ + c];
  __syncthreads();
  int oc = blockIdx.y * 32 + threadIdx.x;  // dest col  = k
  int or0 = blockIdx.x * 32;               // dest row  = n
#pragma unroll
  for (int j = threadIdx.y; j < 32; j += 8)
    dst[(size_t)(or0 + j) * D_ + oc] = f2bf(tile[threadIdx.x][j]);
}

// ---------------- GEMM: C[M][N] = A[M][K] * Bt[N][K]^T ----------------
// EPI=0: scatter to Q (pre-scaled), K as [b,h,s,d]; V transposed to [b,h,d,s].
// EPI=1: f32 out + bias.
template <int EPI>
__global__ __launch_bounds__(256, 2)
void gemm_bt_kernel(const uint16_t* __restrict__ A, const uint16_t* __restrict__ Bt,
                    uint16_t* __restrict__ Cb, float* __restrict__ Cf,
                    const float* __restrict__ bias, int K) {
  __shared__ uint16_t lds[2][2][128 * 32];   // [buf][A/B][row][k] linear
  const int tid = threadIdx.x;
  const int lane = tid & 63;
  const int wid = tid >> 6;
  const int lo = lane & 15, hi = lane >> 4;
  const int row0 = blockIdx.y * 128, col0 = blockIdx.x * 128;
  const int wr = (wid >> 1) * 64, wc = (wid & 1) * 64;

  const uint16_t* gA = A + (size_t)(row0 + (tid >> 2)) * K + (tid & 3) * 8;
  const uint16_t* gB = Bt + (size_t)(col0 + (tid >> 2)) * K + (tid & 3) * 8;

  f32x4 acc[4][4] = {};

  auto stage = [&](int kt, int buf) {
    const uint16_t* a = gA + kt * 32;
    const uint16_t* b = gB + kt * 32;
    char* la = (char*)&lds[buf][0][0] + tid * 16;
    char* lb = (char*)&lds[buf][1][0] + tid * 16;
    GLD16(a, la);
    GLD16(a + (size_t)64 * K, la + 4096);
    GLD16(b, lb);
    GLD16(b + (size_t)64 * K, lb + 4096);
  };

  const int nk = K >> 5;
  stage(0, 0);
  __syncthreads();
  for (int kt = 0; kt < nk; ++kt) {
    const int cur = kt & 1;
    if (kt + 1 < nk) stage(kt + 1, cur ^ 1);
    const uint16_t* lA = &lds[cur][0][0];
    const uint16_t* lB = &lds[cur][1][0];
    bf16x8 af[4], bfr[4];
#pragma unroll
    for (int m = 0; m < 4; ++m)
      af[m] = *(const bf16x8*)(lA + (wr + m * 16 + lo) * 32 + hi * 8);
#pragma unroll
    for (int n = 0; n < 4; ++n)
      bfr[n] = *(const bf16x8*)(lB + (wc + n * 16 + lo) * 32 + hi * 8);
#pragma unroll
    for (int m = 0; m < 4; ++m)
#pragma unroll
      for (int n = 0; n < 4; ++n)
        acc[m][n] = __builtin_amdgcn_mfma_f32_16x16x32_bf16(af[m], bfr[n], acc[m][n], 0, 0, 0);
    __syncthreads();
  }

#pragma unroll
  for (int m = 0; m < 4; ++m)
#pragma unroll
    for (int n = 0; n < 4; ++n) {
      const int gr0 = row0 + wr + m * 16 + hi * 4;  // 4 consecutive rows (j)
      const int gc = col0 + wc + n * 16 + lo;
      if (EPI == 0) {
        const int which = gc >> 10, c = gc & 1023;
        const int hh = c >> 6, d = c & 63;
        const int bb = gr0 >> 11, s0 = gr0 & 2047;
        if (which == 2) {
          // V^T: [b][h][d][s] -- 4 consecutive s pack into one 8B write
          ushort4 pk;
          pk.x = f2bf(acc[m][n][0]); pk.y = f2bf(acc[m][n][1]);
          pk.z = f2bf(acc[m][n][2]); pk.w = f2bf(acc[m][n][3]);
          *reinterpret_cast<ushort4*>(
              &Cb[2 * HSZ + ((size_t)(bb * H_ + hh) * HD_ + d) * S_ + s0]) = pk;
        } else {
          const float qs = (which == 0) ? SC2F : 1.0f;
#pragma unroll
          for (int j = 0; j < 4; ++j)
            Cb[(size_t)which * HSZ + (((size_t)(bb * H_ + hh) * S_ + s0 + j) * HD_ + d)] =
                f2bf(acc[m][n][j] * qs);
        }
      } else {
#pragma unroll
        for (int j = 0; j < 4; ++j)
          Cf[(size_t)(gr0 + j) * D_ + gc] = acc[m][n][j] + bias[gc];
      }
    }
}

// ---------------- causal flash attention (swapped-QK^T, balanced grid) ----------
// 512 blocks: g=(u,s); u=(p,h,b); q-tile = s?15-p:p  => blocks g and g+256 land on
// the same CU and sum to a uniform 34 KV-iterations.
// 4 waves x 32 q-rows, KVBLK=64, K/V^T double-buffered via global_load_lds.
__global__ __launch_bounds__(256, 2)
void attn_kernel(const uint16_t* __restrict__ QKV, uint16_t* __restrict__ ctx) {
  __shared__ uint16_t ldsKV[2][2][4096];  // [buf][K/V][ks*2048 + row*32 + col8]
  __shared__ uint16_t ldsP[128][72];      // P[q][kv], pad 64->72

  const int tid = threadIdx.x;
  const int lane = tid & 63;
  const int w = tid >> 6;
  const int lo = lane & 15, hi = lane >> 4;

  const int g = blockIdx.x;
  const int u = g & 255, sflip = g >> 8;
  const int p = u & 7, h = (u >> 3) & 15, b = u >> 7;
  const int qt = sflip ? 15 - p : p;

  const size_t bh = ((size_t)(b * H_ + h)) * S_ * HD_;
  const uint16_t* Q  = QKV + bh;                 // [s][d], pre-scaled
  const uint16_t* Kp = QKV + HSZ + bh;           // [s][d]
  const uint16_t* Vt = QKV + 2 * HSZ + bh;       // [d][s]

  const int q0w = qt * 128 + w * 32;

  // Q fragments (B-operand of mfma(K,Q)): lane lo = q col, 8 consecutive d
  bf16x8 qf[2][2];
#pragma unroll
  for (int mm = 0; mm < 2; ++mm)
#pragma unroll
    for (int ks = 0; ks < 2; ++ks)
      qf[mm][ks] = *(const bf16x8*)(Q + (size_t)(q0w + mm * 16 + lo) * HD_ + ks * 32 + hi * 8);

  f32x4 acco[2][4] = {};
  float mstate[2] = {-1e30f, -1e30f};
  float lstate[2] = {0.f, 0.f};

  const int nkv = (qt + 1) * 2;

  auto stage = [&](int kt, int bufi) {
    const uint16_t* gk = Kp + (size_t)(kt * 64 + (tid >> 2)) * HD_ + (tid & 3) * 8;
    char* lk = (char*)&ldsKV[bufi][0][0] + tid * 16;
    GLD16(gk, lk);
    GLD16(gk + 32, lk + 4096);
    const uint16_t* gv = Vt + (size_t)(tid >> 2) * S_ + kt * 64 + (tid & 3) * 8;
    char* lv = (char*)&ldsKV[bufi][1][0] + tid * 16;
    GLD16(gv, lv);
    GLD16(gv + 32, lv + 4096);
  };

  stage(0, 0);
  __syncthreads();
  int buf = 0;
  for (int kt = 0; kt < nkv; ++kt) {
    const int kv0 = kt * 64;
    if (kt + 1 < nkv) stage(kt + 1, buf ^ 1);

    if (kv0 < q0w + 32) {  // wave not fully above the diagonal
      // ---- S^T = K Q^T : lane holds col q = lo, rows kv = n*16+hi*4+j ----
      const uint16_t* lK = &ldsKV[buf][0][0];
      bf16x8 ak[4][2];
#pragma unroll
      for (int n = 0; n < 4; ++n)
#pragma unroll
        for (int ks = 0; ks < 2; ++ks)
          ak[n][ks] = *(const bf16x8*)(lK + ks * 2048 + (n * 16 + lo) * 32 + hi * 8);

      f32x4 st[4][2];
      __builtin_amdgcn_s_setprio(1);
#pragma unroll
      for (int n = 0; n < 4; ++n)
#pragma unroll
        for (int mm = 0; mm < 2; ++mm) {
          f32x4 z = {};
          z = __builtin_amdgcn_mfma_f32_16x16x32_bf16(ak[n][0], qf[mm][0], z, 0, 0, 0);
          st[n][mm] = __builtin_amdgcn_mfma_f32_16x16x32_bf16(ak[n][1], qf[mm][1], z, 0, 0, 0);
        }
      __builtin_amdgcn_s_setprio(0);

      // ---- causal mask (only near the diagonal) ----
      if (kv0 + 63 > q0w) {
#pragma unroll
        for (int n = 0; n < 4; ++n)
#pragma unroll
          for (int mm = 0; mm < 2; ++mm)
#pragma unroll
            for (int j = 0; j < 4; ++j) {
              int kvg = kv0 + n * 16 + hi * 4 + j;
              int qg = q0w + mm * 16 + lo;
              if (kvg > qg) st[n][mm][j] = -1e30f;
            }
      }

      // ---- online softmax: row q = lo is (mostly) lane-local ----
      float scf[2];
#pragma unroll
      for (int mm = 0; mm < 2; ++mm) {
        float vmax = st[0][mm][0];
#pragma unroll
        for (int n = 0; n < 4; ++n)
#pragma unroll
          for (int j = 0; j < 4; ++j) vmax = fmaxf(vmax, st[n][mm][j]);
        vmax = fmaxf(vmax, __shfl_xor(vmax, 16));
        vmax = fmaxf(vmax, __shfl_xor(vmax, 32));
        float mnew = fmaxf(mstate[mm], vmax);
        float sc = exp2f(mstate[mm] - mnew);
        mstate[mm] = mnew;
        float rsum = 0.f;
#pragma unroll
        for (int n = 0; n < 4; ++n)
#pragma unroll
          for (int j = 0; j < 4; ++j) {
            float pv = exp2f(st[n][mm][j] - mnew);
            st[n][mm][j] = pv;
            rsum += pv;
          }
        rsum += __shfl_xor(rsum, 16);
        rsum += __shfl_xor(rsum, 32);
        lstate[mm] = lstate[mm] * sc + rsum;
        scf[mm] = sc;
      }

      // ---- write P[q][kv]: 4 j's are consecutive kv -> packed 8B writes ----
#pragma unroll
      for (int mm = 0; mm < 2; ++mm)
#pragma unroll
        for (int n = 0; n < 4; ++n) {
          ushort4 pk;
          pk.x = f2bf(st[n][mm][0]); pk.y = f2bf(st[n][mm][1]);
          pk.z = f2bf(st[n][mm][2]); pk.w = f2bf(st[n][mm][3]);
          *reinterpret_cast<ushort4*>(&ldsP[w * 32 + mm * 16 + lo][n * 16 + hi * 4]) = pk;
        }

      // ---- rescale O (sc lives at lane lo=q; O rows are q=hi*4+j) ----
#pragma unroll
      for (int qb = 0; qb < 2; ++qb)
#pragma unroll
        for (int j = 0; j < 4; ++j) {
          float s0 = __shfl(scf[qb], hi * 4 + j);
#pragma unroll
          for (int nd = 0; nd < 4; ++nd) acco[qb][nd][j] *= s0;
        }

      // ---- O += P V ----
      const uint16_t* lV = &ldsKV[buf][1][0];
      bf16x8 ap[2][2], bv[4][2];
#pragma unroll
      for (int qb = 0; qb < 2; ++qb)
#pragma unroll
        for (int ks = 0; ks < 2; ++ks)
          ap[qb][ks] = *(const bf16x8*)(&ldsP[w * 32 + qb * 16 + lo][ks * 32 + hi * 8]);
#pragma unroll
      for (int nd = 0; nd < 4; ++nd)
#pragma unroll
        for (int ks = 0; ks < 2; ++ks)
          bv[nd][ks] = *(const bf16x8*)(lV + ks * 2048 + (nd * 16 + lo) * 32 + hi * 8);
      __builtin_amdgcn_s_setprio(1);
#pragma unroll
      for (int qb = 0; qb < 2; ++qb)
#pragma unroll
        for (int nd = 0; nd < 4; ++nd) {
          acco[qb][nd] = __builtin_amdgcn_mfma_f32_16x16x32_bf16(ap[qb][0], bv[nd][0], acco[qb][nd], 0, 0, 0);
          acco[qb][nd] = __builtin_amdgcn_mfma_f32_16x16x32_bf16(ap[qb][1], bv[nd][1], acco[qb][nd], 0, 0, 0);
        }
      __builtin_amdgcn_s_setprio(0);
    }

    __syncthreads();
    buf ^= 1;
  }

  // ---- normalize + write ctx [b*S+q][h*64+d] bf16 ----
  float rl[2] = {1.f / lstate[0], 1.f / lstate[1]};
#pragma unroll
  for (int qb = 0; qb < 2; ++qb)
#pragma unroll
    for (int j = 0; j < 4; ++j) {
      float inv = __shfl(rl[qb], hi * 4 + j);
      int qg = q0w + qb * 16 + hi * 4 + j;
      size_t row = (size_t)b * S_ + qg;
#pragma unroll
      for (int nd = 0; nd < 4; ++nd)
        ctx[row * D_ + h * HD_ + nd * 16 + lo] = f2bf(acco[qb][nd][j] * inv);
    }
}

extern "C" void kernel_launch(void* const* d_in, const int* in_sizes, int n_in,
                              void* d_out, int out_size, void* d_ws, size_t ws_size,
                              hipStream_t stream) {
  (void)in_sizes; (void)n_in; (void)out_size; (void)ws_size;
  const float* x  = (const float*)d_in[0];
  const float* Wq = (const float*)d_in[1];
  const float* Wk = (const float*)d_in[2];
  const float* Wv = (const float*)d_in[3];
  const float* Wo = (const float*)d_in[4];
  const float* bo = (const float*)d_in[5];
  float* out = (float*)d_out;

  uint16_t* ws  = (uint16_t*)d_ws;
  uint16_t* xb  = ws;                         // 4096*1024
  uint16_t* Wt  = xb + (size_t)M_ * D_;       // 4*1024*1024
  uint16_t* QKV = Wt + (size_t)4 * D_ * D_;   // 3*HSZ (Q, K, V^T)
  uint16_t* ctx = QKV + 3 * HSZ;              // 4096*1024   (~50 MB total)

  cvt_x_kernel<<<(M_ * D_) / 1024, 256, 0, stream>>>(x, xb);
  tr_w_kernel<<<dim3(32, 32, 4), dim3(32, 8), 0, stream>>>(Wq, Wk, Wv, Wo, Wt);
  gemm_bt_kernel<0><<<dim3(3072 / 128, M_ / 128), 256, 0, stream>>>(xb, Wt, QKV, nullptr, nullptr, D_);
  attn_kernel<<<512, 256, 0, stream>>>(QKV, ctx);
  gemm_bt_kernel<1><<<dim3(D_ / 128, M_ / 128), 256, 0, stream>>>(ctx, Wt + (size_t)3 * D_ * D_, nullptr, out, bo, D_);
}

// Round 3
// 126.686 us; speedup vs baseline: 1.7269x; 1.0929x over previous
//
#include <hip/hip_runtime.h>
#include <stdint.h>

typedef __bf16 bf16x8 __attribute__((ext_vector_type(8)));
typedef float f32x4 __attribute__((ext_vector_type(4)));

static constexpr int B_ = 2, S_ = 2048, D_ = 1024, H_ = 16, HD_ = 64;
static constexpr int M_ = B_ * S_;                         // 4096
static constexpr size_t HSZ = (size_t)B_ * H_ * S_ * HD_;  // 4,194,304 elems per Q/K/V

#define DEV_INLINE __device__ __forceinline__

// 1/sqrt(HD) * log2(e) -- folded into Q at projection time (softmax runs base-2)
#define SC2F (0.125f * 1.4426950408889634f)

DEV_INLINE uint16_t f2bf(float f) {
  __bf16 h = (__bf16)f;  // RNE; compiler packs pairs into v_cvt_pk_bf16_f32
  return __builtin_bit_cast(uint16_t, h);
}

#define GLD16(gptr, lptr)                                                        \
  __builtin_amdgcn_global_load_lds(                                              \
      (const __attribute__((address_space(1))) void*)(gptr),                     \
      (__attribute__((address_space(3))) void*)(lptr), 16, 0, 0)

// ---------------- x -> bf16 ----------------
__global__ void cvt_x_kernel(const float* __restrict__ x, uint16_t* __restrict__ xb) {
  int i = blockIdx.x * 256 + threadIdx.x;
  float4 v = reinterpret_cast<const float4*>(x)[i];
  ushort4 o;
  o.x = f2bf(v.x); o.y = f2bf(v.y); o.z = f2bf(v.z); o.w = f2bf(v.w);
  reinterpret_cast<ushort4*>(xb)[i] = o;
}

// ---------------- W (4x) -> W^T bf16, concatenated [4*1024][1024] ----------------
__global__ void tr_w_kernel(const float* __restrict__ W0, const float* __restrict__ W1,
                            const float* __restrict__ W2, const float* __restrict__ W3,
                            uint16_t* __restrict__ Wt) {
  __shared__ float tile[32][33];
  const float* W = (blockIdx.z == 0) ? W0 : (blockIdx.z == 1) ? W1
                   : (blockIdx.z == 2) ? W2 : W3;
  uint16_t* dst = Wt + (size_t)blockIdx.z * D_ * D_;
  int c = blockIdx.x * 32 + threadIdx.x;   // source col n
  int r0 = blockIdx.y * 32;                // source row k
#pragma unroll
  for (int j = threadIdx.y; j < 32; j += 8)
    tile[j][threadIdx.x] = W[(size_t)(r0 + j) * D_ + c];
  __syncthreads();
  int oc = blockIdx.y * 32 + threadIdx.x;  // dest col  = k
  int or0 = blockIdx.x * 32;               // dest row  = n
#pragma unroll
  for (int j = threadIdx.y; j < 32; j += 8)
    dst[(size_t)(or0 + j) * D_ + oc] = f2bf(tile[threadIdx.x][j]);
}

// ---------------- GEMM: C[M][N] = A[M][K] * Bt[N][K]^T ----------------
// EPI=0: scatter to Q (pre-scaled), K as [b,h,s,d]; V transposed to [b,h,d,s].
// EPI=1: f32 out + bias.
template <int EPI>
__global__ __launch_bounds__(256, 2)
void gemm_bt_kernel(const uint16_t* __restrict__ A, const uint16_t* __restrict__ Bt,
                    uint16_t* __restrict__ Cb, float* __restrict__ Cf,
                    const float* __restrict__ bias, int K) {
  __shared__ uint16_t lds[2][2][128 * 32];   // [buf][A/B][row][k] linear
  const int tid = threadIdx.x;
  const int lane = tid & 63;
  const int wid = tid >> 6;
  const int lo = lane & 15, hi = lane >> 4;
  const int row0 = blockIdx.y * 128, col0 = blockIdx.x * 128;
  const int wr = (wid >> 1) * 64, wc = (wid & 1) * 64;

  const uint16_t* gA = A + (size_t)(row0 + (tid >> 2)) * K + (tid & 3) * 8;
  const uint16_t* gB = Bt + (size_t)(col0 + (tid >> 2)) * K + (tid & 3) * 8;

  f32x4 acc[4][4] = {};

  auto stage = [&](int kt, int buf) {
    const uint16_t* a = gA + kt * 32;
    const uint16_t* b = gB + kt * 32;
    char* la = (char*)&lds[buf][0][0] + tid * 16;
    char* lb = (char*)&lds[buf][1][0] + tid * 16;
    GLD16(a, la);
    GLD16(a + (size_t)64 * K, la + 4096);
    GLD16(b, lb);
    GLD16(b + (size_t)64 * K, lb + 4096);
  };

  const int nk = K >> 5;
  stage(0, 0);
  __syncthreads();
  for (int kt = 0; kt < nk; ++kt) {
    const int cur = kt & 1;
    if (kt + 1 < nk) stage(kt + 1, cur ^ 1);
    const uint16_t* lA = &lds[cur][0][0];
    const uint16_t* lB = &lds[cur][1][0];
    bf16x8 af[4], bfr[4];
#pragma unroll
    for (int m = 0; m < 4; ++m)
      af[m] = *(const bf16x8*)(lA + (wr + m * 16 + lo) * 32 + hi * 8);
#pragma unroll
    for (int n = 0; n < 4; ++n)
      bfr[n] = *(const bf16x8*)(lB + (wc + n * 16 + lo) * 32 + hi * 8);
    __builtin_amdgcn_s_setprio(1);
#pragma unroll
    for (int m = 0; m < 4; ++m)
#pragma unroll
      for (int n = 0; n < 4; ++n)
        acc[m][n] = __builtin_amdgcn_mfma_f32_16x16x32_bf16(af[m], bfr[n], acc[m][n], 0, 0, 0);
    __builtin_amdgcn_s_setprio(0);
    __syncthreads();
  }

#pragma unroll
  for (int m = 0; m < 4; ++m)
#pragma unroll
    for (int n = 0; n < 4; ++n) {
      const int gr0 = row0 + wr + m * 16 + hi * 4;  // 4 consecutive rows (j)
      const int gc = col0 + wc + n * 16 + lo;
      if (EPI == 0) {
        const int which = gc >> 10, c = gc & 1023;
        const int hh = c >> 6, d = c & 63;
        const int bb = gr0 >> 11, s0 = gr0 & 2047;
        if (which == 2) {
          // V^T: [b][h][d][s] -- 4 consecutive s pack into one 8B write
          ushort4 pk;
          pk.x = f2bf(acc[m][n][0]); pk.y = f2bf(acc[m][n][1]);
          pk.z = f2bf(acc[m][n][2]); pk.w = f2bf(acc[m][n][3]);
          *reinterpret_cast<ushort4*>(
              &Cb[2 * HSZ + ((size_t)(bb * H_ + hh) * HD_ + d) * S_ + s0]) = pk;
        } else {
          const float qs = (which == 0) ? SC2F : 1.0f;
#pragma unroll
          for (int j = 0; j < 4; ++j)
            Cb[(size_t)which * HSZ + (((size_t)(bb * H_ + hh) * S_ + s0 + j) * HD_ + d)] =
                f2bf(acc[m][n][j] * qs);
        }
      } else {
#pragma unroll
        for (int j = 0; j < 4; ++j)
          Cf[(size_t)(gr0 + j) * D_ + gc] = acc[m][n][j] + bias[gc];
      }
    }
}

// ---------------- causal flash attention -------------------------------------
// 512 blocks: g -> (p, h, b); block sequentially sweeps q-tiles p and 31-p
// (QBLK=64) => every block does exactly 33 KV-iterations (KVBLK=64). 4 waves,
// wave owns 16 q rows. Swapped QK^T (S^T) AND transposed PV (O^T) so the
// entire softmax state (m, l, rescale) is per-lane (lane lo = q).
__global__ __launch_bounds__(256, 2)
void attn_kernel(const uint16_t* __restrict__ QKV, uint16_t* __restrict__ ctx) {
  __shared__ uint16_t ldsKV[2][2][4096];  // [buf][K/V][ks*2048 + row*32 + col8]
  __shared__ uint16_t ldsP[64][72];       // P[q][kv], pad 64->72

  const int tid = threadIdx.x;
  const int lane = tid & 63;
  const int w = tid >> 6;
  const int lo = lane & 15, hi = lane >> 4;

  const int g = blockIdx.x;
  const int p = g & 15, h = (g >> 4) & 15, b = g >> 8;

  const size_t bh = ((size_t)(b * H_ + h)) * S_ * HD_;
  const uint16_t* Q  = QKV + bh;                 // [s][d], pre-scaled by SC2F
  const uint16_t* Kp = QKV + HSZ + bh;           // [s][d]
  const uint16_t* Vt = QKV + 2 * HSZ + bh;       // [d][s]

  auto stage = [&](int kt, int bufi) {
    const uint16_t* gk = Kp + (size_t)(kt * 64 + (tid >> 2)) * HD_ + (tid & 3) * 8;
    char* lk = (char*)&ldsKV[bufi][0][0] + tid * 16;
    GLD16(gk, lk);
    GLD16(gk + 32, lk + 4096);
    const uint16_t* gv = Vt + (size_t)(tid >> 2) * S_ + kt * 64 + (tid & 3) * 8;
    char* lv = (char*)&ldsKV[bufi][1][0] + tid * 16;
    GLD16(gv, lv);
    GLD16(gv + 32, lv + 4096);
  };

  auto sweep = [&](int qt, int nkv) {
    const int q0w = qt * 64 + w * 16;
    // Q fragments (B-operand of mfma(K,Q)): lane lo = q col, hi*8 = d
    bf16x8 qf[2];
#pragma unroll
    for (int ks = 0; ks < 2; ++ks)
      qf[ks] = *(const bf16x8*)(Q + (size_t)(q0w + lo) * HD_ + ks * 32 + hi * 8);

    f32x4 acco[4] = {};              // O^T: lane lo = q, row = d (nd*16+hi*4+j)
    float mstate = -1e30f, lstate = 0.f;

    stage(0, 0);
    __syncthreads();
    int buf = 0;
    for (int kt = 0; kt < nkv; ++kt) {
      if (kt + 1 < nkv) stage(kt + 1, buf ^ 1);

      // ---- S^T = K Q^T : lane lo = q, rows kv = n*16+hi*4+j ----
      const uint16_t* lK = &ldsKV[buf][0][0];
      bf16x8 ak[4][2];
#pragma unroll
      for (int n = 0; n < 4; ++n)
#pragma unroll
        for (int ks = 0; ks < 2; ++ks)
          ak[n][ks] = *(const bf16x8*)(lK + ks * 2048 + (n * 16 + lo) * 32 + hi * 8);

      f32x4 st[4];
      __builtin_amdgcn_s_setprio(1);
#pragma unroll
      for (int n = 0; n < 4; ++n) {
        f32x4 z = {};
        z = __builtin_amdgcn_mfma_f32_16x16x32_bf16(ak[n][0], qf[0], z, 0, 0, 0);
        st[n] = __builtin_amdgcn_mfma_f32_16x16x32_bf16(ak[n][1], qf[1], z, 0, 0, 0);
      }
      __builtin_amdgcn_s_setprio(0);

      // ---- causal mask (diagonal tile only) ----
      if (kt == nkv - 1) {
        const int qg = q0w + lo;
#pragma unroll
        for (int n = 0; n < 4; ++n)
#pragma unroll
          for (int j = 0; j < 4; ++j) {
            int kvg = kt * 64 + n * 16 + hi * 4 + j;
            if (kvg > qg) st[n][j] = -1e30f;
          }
      }

      // ---- online softmax, fully per-lane state (q = lo) ----
      float vmax = st[0][0];
#pragma unroll
      for (int n = 0; n < 4; ++n)
#pragma unroll
        for (int j = 0; j < 4; ++j) vmax = fmaxf(vmax, st[n][j]);
      vmax = fmaxf(vmax, __shfl_xor(vmax, 16));
      vmax = fmaxf(vmax, __shfl_xor(vmax, 32));

      if (__any(vmax > mstate + 8.f)) {   // defer-max: rescale only when needed
        float mnew = fmaxf(mstate, vmax);
        float sc = exp2f(mstate - mnew);
        mstate = mnew;
        lstate *= sc;
#pragma unroll
        for (int nd = 0; nd < 4; ++nd)
#pragma unroll
          for (int j = 0; j < 4; ++j) acco[nd][j] *= sc;
      }

      float rsum = 0.f;
#pragma unroll
      for (int n = 0; n < 4; ++n)
#pragma unroll
        for (int j = 0; j < 4; ++j) {
          float pv = exp2f(st[n][j] - mstate);
          st[n][j] = pv;
          rsum += pv;
        }
      rsum += __shfl_xor(rsum, 16);
      rsum += __shfl_xor(rsum, 32);
      lstate += rsum;

      // ---- write P[q][kv] (4 consecutive kv -> packed 8B, wave-local rows) ----
#pragma unroll
      for (int n = 0; n < 4; ++n) {
        ushort4 pk;
        pk.x = f2bf(st[n][0]); pk.y = f2bf(st[n][1]);
        pk.z = f2bf(st[n][2]); pk.w = f2bf(st[n][3]);
        *reinterpret_cast<ushort4*>(&ldsP[w * 16 + lo][n * 16 + hi * 4]) = pk;
      }

      // ---- O^T += V^T P^T : A = V^T frag, B = P^T frag (row-read of P) ----
      const uint16_t* lV = &ldsKV[buf][1][0];
      bf16x8 ap[2], bv[4][2];
#pragma unroll
      for (int ks = 0; ks < 2; ++ks)
        ap[ks] = *(const bf16x8*)(&ldsP[w * 16 + lo][ks * 32 + hi * 8]);
#pragma unroll
      for (int nd = 0; nd < 4; ++nd)
#pragma unroll
        for (int ks = 0; ks < 2; ++ks)
          bv[nd][ks] = *(const bf16x8*)(lV + ks * 2048 + (nd * 16 + lo) * 32 + hi * 8);
      __builtin_amdgcn_s_setprio(1);
#pragma unroll
      for (int nd = 0; nd < 4; ++nd) {
        acco[nd] = __builtin_amdgcn_mfma_f32_16x16x32_bf16(bv[nd][0], ap[0], acco[nd], 0, 0, 0);
        acco[nd] = __builtin_amdgcn_mfma_f32_16x16x32_bf16(bv[nd][1], ap[1], acco[nd], 0, 0, 0);
      }
      __builtin_amdgcn_s_setprio(0);

      __syncthreads();
      buf ^= 1;
    }

    // ---- normalize (per-lane) + packed ctx write: row q = q0w+lo ----
    const float inv = 1.f / lstate;
    uint16_t* crow = ctx + (size_t)(b * S_ + q0w + lo) * D_ + h * HD_;
#pragma unroll
    for (int nd = 0; nd < 4; ++nd) {
      ushort4 pk;
      pk.x = f2bf(acco[nd][0] * inv); pk.y = f2bf(acco[nd][1] * inv);
      pk.z = f2bf(acco[nd][2] * inv); pk.w = f2bf(acco[nd][3] * inv);
      *reinterpret_cast<ushort4*>(crow + nd * 16 + hi * 4) = pk;
    }
  };

  sweep(p, p + 1);
  __syncthreads();
  sweep(31 - p, 32 - p);
}

extern "C" void kernel_launch(void* const* d_in, const int* in_sizes, int n_in,
                              void* d_out, int out_size, void* d_ws, size_t ws_size,
                              hipStream_t stream) {
  (void)in_sizes; (void)n_in; (void)out_size; (void)ws_size;
  const float* x  = (const float*)d_in[0];
  const float* Wq = (const float*)d_in[1];
  const float* Wk = (const float*)d_in[2];
  const float* Wv = (const float*)d_in[3];
  const float* Wo = (const float*)d_in[4];
  const float* bo = (const float*)d_in[5];
  float* out = (float*)d_out;

  uint16_t* ws  = (uint16_t*)d_ws;
  uint16_t* xb  = ws;                         // 4096*1024
  uint16_t* Wt  = xb + (size_t)M_ * D_;       // 4*1024*1024
  uint16_t* QKV = Wt + (size_t)4 * D_ * D_;   // 3*HSZ (Q, K, V^T)
  uint16_t* ctx = QKV + 3 * HSZ;              // 4096*1024   (~50 MB total)

  cvt_x_kernel<<<(M_ * D_) / 1024, 256, 0, stream>>>(x, xb);
  tr_w_kernel<<<dim3(32, 32, 4), dim3(32, 8), 0, stream>>>(Wq, Wk, Wv, Wo, Wt);
  gemm_bt_kernel<0><<<dim3(3072 / 128, M_ / 128), 256, 0, stream>>>(xb, Wt, QKV, nullptr, nullptr, D_);
  attn_kernel<<<512, 256, 0, stream>>>(QKV, ctx);
  gemm_bt_kernel<1><<<dim3(D_ / 128, M_ / 128), 256, 0, stream>>>(ctx, Wt + (size_t)3 * D_ * D_, nullptr, out, bo, D_);
}